// Round 1
// baseline (899.703 us; speedup 1.0000x reference)
//
#include <hip/hip_runtime.h>

// EntityMarker: inclusive span-mean over sequence_output rows.
//   sequence_output: [B, L, H] fp32, B=128, L=2048, H=768
//   entity_positions: [B, 4] int32 (h_start, h_end, t_start, t_end raw)
//   out: head [B,H] then tail [B,H], fp32, concatenated flat.
//
// Strategy: memory-bound gather-reduce. Split each of the 2*B spans into
// CHUNKS chunks for load balance (span len varies 1..2048). Each block:
// 192 threads, one float4 column per thread -> each row read is one
// coalesced 3 KB wave access. Chunk partial sums are pre-scaled by 1/count
// and combined with fp32 atomicAdd into d_out (zeroed via hipMemsetAsync).

#define L_SEQ  2048
#define H_DIM  768
#define CHUNKS 16
#define TPB    192   // H_DIM/4 float4 columns, 3 waves

__global__ __launch_bounds__(TPB) void entity_span_mean_kernel(
    const float* __restrict__ seq,   // [B, L, H]
    const int*   __restrict__ pos,   // [B, 4]
    float*       __restrict__ out,   // [2, B, H]
    int B)
{
    const int blk     = blockIdx.x;
    const int chunk   = blk % CHUNKS;
    const int span_id = blk / CHUNKS;     // 0 .. 2B-1
    const int ent     = span_id & 1;      // 0 = head, 1 = tail
    const int b       = span_id >> 1;

    const int p0 = pos[b * 4 + 2 * ent + 0];
    const int p1 = pos[b * 4 + 2 * ent + 1];
    const int s  = min(max(p0, 0), L_SEQ - 1);
    const int e  = max(s, min(p1, L_SEQ - 1));
    const int len = e - s + 1;            // count >= 1

    // This chunk's row range [r0, r1)
    const int per = (len + CHUNKS - 1) / CHUNKS;
    const int r0  = s + chunk * per;
    const int r1  = min(r0 + per, e + 1);
    if (r0 >= r1) return;                 // empty chunk

    const int col = threadIdx.x;          // float4 column, 0..191
    const float4* __restrict__ base =
        (const float4*)(seq + (size_t)b * L_SEQ * H_DIM);

    // Two accumulators for a bit of ILP on the dependent add chain.
    float4 acc0 = make_float4(0.f, 0.f, 0.f, 0.f);
    float4 acc1 = make_float4(0.f, 0.f, 0.f, 0.f);
    int r = r0;
    for (; r + 1 < r1; r += 2) {
        float4 v0 = base[(size_t)r       * (H_DIM / 4) + col];
        float4 v1 = base[(size_t)(r + 1) * (H_DIM / 4) + col];
        acc0.x += v0.x; acc0.y += v0.y; acc0.z += v0.z; acc0.w += v0.w;
        acc1.x += v1.x; acc1.y += v1.y; acc1.z += v1.z; acc1.w += v1.w;
    }
    if (r < r1) {
        float4 v0 = base[(size_t)r * (H_DIM / 4) + col];
        acc0.x += v0.x; acc0.y += v0.y; acc0.z += v0.z; acc0.w += v0.w;
    }

    const float inv = 1.0f / (float)len;
    float* o = out + (size_t)ent * B * H_DIM + (size_t)b * H_DIM + col * 4;
    atomicAdd(o + 0, (acc0.x + acc1.x) * inv);
    atomicAdd(o + 1, (acc0.y + acc1.y) * inv);
    atomicAdd(o + 2, (acc0.z + acc1.z) * inv);
    atomicAdd(o + 3, (acc0.w + acc1.w) * inv);
}

extern "C" void kernel_launch(void* const* d_in, const int* in_sizes, int n_in,
                              void* d_out, int out_size, void* d_ws, size_t ws_size,
                              hipStream_t stream) {
    const float* seq = (const float*)d_in[0];
    const int*   pos = (const int*)d_in[1];
    float*       out = (float*)d_out;

    const int B = in_sizes[1] / 4;        // 128

    // d_out is poisoned to 0xAA before every timed launch — zero it.
    hipMemsetAsync(d_out, 0, (size_t)out_size * sizeof(float), stream);

    const int n_blocks = 2 * B * CHUNKS;  // 4096
    entity_span_mean_kernel<<<n_blocks, TPB, 0, stream>>>(seq, pos, out, B);
}